// Round 1
// baseline (114.203 us; speedup 1.0000x reference)
//
#include <hip/hip_runtime.h>

#define SGRID 32
#define SGRID3 (SGRID * SGRID * SGRID)

__global__ void zero_out_kernel(float* out) { out[0] = 0.0f; }

__device__ __forceinline__ float dist_to_cell(float sx, float sy, float sz,
                                              const float* __restrict__ cb) {
    // clamp to [0, 32]
    float cx = fminf(fmaxf(sx, 0.0f), (float)SGRID);
    float cy = fminf(fmaxf(sy, 0.0f), (float)SGRID);
    float cz = fminf(fmaxf(sz, 0.0f), (float)SGRID);
    // int cast (trunc == floor since >=0), clamp to 31
    int ix = min((int)cx, SGRID - 1);
    int iy = min((int)cy, SGRID - 1);
    int iz = min((int)cz, SGRID - 1);
    int flat = ix * (SGRID * SGRID) + iy * SGRID + iz;
    const float* c = cb + (size_t)flat * 3;
    float dx = sx - c[0];
    float dy = sy - c[1];
    float dz = sz - c[2];
    return sqrtf(dx * dx + dy * dy + dz * dz);
}

__launch_bounds__(256)
__global__ void sym_loss_kernel(const float* __restrict__ output,
                                const float* __restrict__ points,
                                const float* __restrict__ closest,
                                float* __restrict__ out,
                                int N, float invB) {
    const int b = blockIdx.y;
    const int tid = blockIdx.x * blockDim.x + threadIdx.x;  // over ceil(N/4)

    // per-batch params: 6 rows x 4 floats
    const float* prm = output + (size_t)b * 24;
    float pn[3][4];   // planes (nx,ny,nz,d)
    float inv_nn[3];
    float qt[3][4];   // quats (w,x,y,z)
    float qinvn[3];
#pragma unroll
    for (int i = 0; i < 3; i++) {
        pn[i][0] = prm[i * 4 + 0];
        pn[i][1] = prm[i * 4 + 1];
        pn[i][2] = prm[i * 4 + 2];
        pn[i][3] = prm[i * 4 + 3];
        inv_nn[i] = 1.0f / (pn[i][0] * pn[i][0] + pn[i][1] * pn[i][1] + pn[i][2] * pn[i][2]);
        qt[i][0] = prm[12 + i * 4 + 0];
        qt[i][1] = prm[12 + i * 4 + 1];
        qt[i][2] = prm[12 + i * 4 + 2];
        qt[i][3] = prm[12 + i * 4 + 3];
        qinvn[i] = rsqrtf(qt[i][0] * qt[i][0] + qt[i][1] * qt[i][1] +
                          qt[i][2] * qt[i][2] + qt[i][3] * qt[i][3]);
    }

    const float* pb = points + (size_t)b * N * 3;
    const float* cb = closest + (size_t)b * SGRID3 * 3;

    float acc = 0.0f;
    const int base = tid * 4;

    float px[4], py[4], pz[4];
    int npts = 0;
    if (base + 3 < N) {
        // full vector path: 3 x float4 = 12 consecutive floats (4 points)
        const float4* pv = (const float4*)pb;
        float4 v0 = pv[(size_t)tid * 3 + 0];
        float4 v1 = pv[(size_t)tid * 3 + 1];
        float4 v2 = pv[(size_t)tid * 3 + 2];
        px[0] = v0.x; py[0] = v0.y; pz[0] = v0.z;
        px[1] = v0.w; py[1] = v1.x; pz[1] = v1.y;
        px[2] = v1.z; py[2] = v1.w; pz[2] = v2.x;
        px[3] = v2.y; py[3] = v2.z; pz[3] = v2.w;
        npts = 4;
    } else if (base < N) {
        npts = N - base;
        for (int k = 0; k < npts; k++) {
            px[k] = pb[(size_t)(base + k) * 3 + 0];
            py[k] = pb[(size_t)(base + k) * 3 + 1];
            pz[k] = pb[(size_t)(base + k) * 3 + 2];
        }
    }

#pragma unroll
    for (int k = 0; k < 4; k++) {
        if (k >= npts) break;
        float x = px[k], y = py[k], z = pz[k];
        // 3 plane reflections
#pragma unroll
        for (int i = 0; i < 3; i++) {
            float nx = pn[i][0], ny = pn[i][1], nz = pn[i][2];
            float dis = (nx * x + ny * y + nz * z + pn[i][3]) * inv_nn[i];
            float t = 2.0f * dis;
            acc += dist_to_cell(x - t * nx, y - t * ny, z - t * nz, cb);
        }
        // 3 quaternion rotations: rot = (-tw*rv + rw*tv + rv x tv) / |r|
#pragma unroll
        for (int i = 0; i < 3; i++) {
            float rw = qt[i][0], rx = qt[i][1], ry = qt[i][2], rz = qt[i][3];
            float tw = -(rx * x + ry * y + rz * z);
            float tx = rw * x + (ry * z - rz * y);
            float ty = rw * y + (rz * x - rx * z);
            float tz = rw * z + (rx * y - ry * x);
            float n = qinvn[i];
            float ox = (-tw * rx + rw * tx + (ry * tz - rz * ty)) * n;
            float oy = (-tw * ry + rw * ty + (rz * tx - rx * tz)) * n;
            float oz = (-tw * rz + rw * tz + (rx * ty - ry * tx)) * n;
            acc += dist_to_cell(ox, oy, oz, cb);
        }
    }

    // wave64 reduce -> LDS -> one atomic per block
#pragma unroll
    for (int off = 32; off > 0; off >>= 1)
        acc += __shfl_down(acc, off, 64);

    __shared__ float sacc[4];  // 256 threads / 64
    int lane = threadIdx.x & 63;
    int wid = threadIdx.x >> 6;
    if (lane == 0) sacc[wid] = acc;
    __syncthreads();
    if (threadIdx.x == 0) {
        float s = (sacc[0] + sacc[1] + sacc[2] + sacc[3]) * invB;
        atomicAdd(out, s);
    }
}

extern "C" void kernel_launch(void* const* d_in, const int* in_sizes, int n_in,
                              void* d_out, int out_size, void* d_ws, size_t ws_size,
                              hipStream_t stream) {
    const float* output = (const float*)d_in[0];
    const float* points = (const float*)d_in[1];
    const float* closest = (const float*)d_in[2];
    float* out = (float*)d_out;

    int B = in_sizes[0] / 24;              // (B,6,4)
    int N = in_sizes[1] / (3 * B);         // (B,N,3)

    zero_out_kernel<<<1, 1, 0, stream>>>(out);

    int threads = 256;
    int pts_per_block = threads * 4;
    int gx = (N + pts_per_block - 1) / pts_per_block;
    dim3 grid(gx, B);
    sym_loss_kernel<<<grid, threads, 0, stream>>>(output, points, closest, out,
                                                  N, 1.0f / (float)B);
}